// Round 5
// baseline (123.471 us; speedup 1.0000x reference)
//
#include <hip/hip_runtime.h>
#include <math.h>

#define T_LEN 16384
#define B_ROWS 256
#define BLK 256
#define EPT 8                       // elements per thread
#define COLS (BLK * EPT)            // 2048 columns per block
#define SEG (T_LEN / COLS)          // 8 segments per row
#define GRID (B_ROWS * SEG)         // 2048 blocks
#define NBANK 8                     // gacc banks to spread atomic contention

#define LOG2E 1.44269504088896340f
#define LN2   0.69314718055994531f

typedef float v4f __attribute__((ext_vector_type(4)));

// fast sigmoid: 1 v_exp + 1 v_rcp
__device__ __forceinline__ float fast_sig(float x) {
    float e = __builtin_amdgcn_exp2f(fabsf(x) * -LOG2E);
    float r = __builtin_amdgcn_rcpf(1.0f + e);
    return (x >= 0.f) ? r : e * r;
}

// ws layout (floats): gbank[NBANK][8] | rowdiff[B_ROWS] | cnt(uint)
// All cross-block traffic is device-scope atomics (coherent point) — NO
// __threadfence: R3/R4 showed 2048 per-block device-release fences (L2
// writebacks) collapse the whole memory system (VALUBusy 5%, ~100us).

__global__ __launch_bounds__(BLK) void loss_fused(
    const float* __restrict__ pon, const float* __restrict__ poff,
    const float* __restrict__ ton, const float* __restrict__ toff,
    float* __restrict__ ws, float* __restrict__ out)
{
    const int blk = blockIdx.x;
    const int row = blk >> 3;            // SEG = 8
    const int s   = blk & 7;
    const int tid = threadIdx.x;
    const int C0  = s * COLS;            // segment start (row-local col)
    const int c0  = C0 + tid * EPT;      // this thread's first col
    const size_t rowbase = (size_t)row * T_LEN;

    float* gbank   = ws;                              // NBANK*8 floats
    float* rowdiff = ws + NBANK * 8;                  // B_ROWS floats
    unsigned int* cnt = (unsigned int*)(ws + NBANK * 8 + B_ROWS);

    __shared__ float on_h[BLK * 3];      // each thread's first 3 onset probs
    __shared__ float off_h[BLK * 3];     // each thread's first 3 offset probs
    __shared__ float part[4][9];
    __shared__ int   is_last;

    // accumulators (arithmetic form, t/u are exactly 0.0 or 1.0)
    float on_sp = 0.f, on_tsp = 0.f, on_pos = 0.f, on_cnt = 0.f, on_psum = 0.f;
    float off_sp = 0.f, off_tsp = 0.f, off_pos = 0.f, off_cnt = 0.f, off_psum = 0.f;
    float cons = 0.f;
    float w0 = 0.f, w1 = 0.f, w2 = 0.f;  // rolling window of last 3 onset probs

    const float4* pon4  = (const float4*)(pon  + rowbase + c0);
    const float4* poff4 = (const float4*)(poff + rowbase + c0);
    const float4* ton4  = (const float4*)(ton  + rowbase + c0);
    const float4* toff4 = (const float4*)(toff + rowbase + c0);

    #pragma unroll
    for (int k = 0; k < EPT / 4; k++) {
        float4 xo = pon4[k], xf = poff4[k], to = ton4[k], tf = toff4[k];
        float xs[4] = {xo.x, xo.y, xo.z, xo.w};
        float fs[4] = {xf.x, xf.y, xf.z, xf.w};
        float ts[4] = {to.x, to.y, to.z, to.w};
        float us[4] = {tf.x, tf.y, tf.z, tf.w};
        #pragma unroll
        for (int j = 0; j < 4; j++) {
            const int i = 4 * k + j;      // compile-time
            // ---- onset: softplus + sigmoid via exp2/rcp/log2 HW ops ----
            float x  = xs[j], t = ts[j];
            float e  = __builtin_amdgcn_exp2f(fabsf(x) * -LOG2E);
            float r  = __builtin_amdgcn_rcpf(1.0f + e);
            float sp = fmaf(-LN2, __builtin_amdgcn_logf(r), fmaxf(x, 0.f)); // softplus(x)
            on_sp  += sp;
            on_tsp += t * sp;
            on_pos += t * fminf(sp - x, 5.0f);
            on_cnt += t;
            float pr = (x >= 0.f) ? r : e * r;
            on_psum += pr;
            // ---- offset ----
            float y  = fs[j], u = us[j];
            float e2 = __builtin_amdgcn_exp2f(fabsf(y) * -LOG2E);
            float r2 = __builtin_amdgcn_rcpf(1.0f + e2);
            float sp2 = fmaf(-LN2, __builtin_amdgcn_logf(r2), fmaxf(y, 0.f));
            off_sp  += sp2;
            off_tsp += u * sp2;
            off_pos += u * fminf(sp2 - y, 5.0f);
            off_cnt += u;
            float qr = (y >= 0.f) ? r2 : e2 * r2;
            off_psum += qr;
            // ---- halo stash (compile-time branch) ----
            if (i < 3) { on_h[tid * 3 + i] = pr; off_h[tid * 3 + i] = qr; }
            // ---- in-chunk violations: jg = c0+i-3, i>=3 ----
            if (i >= 3) {
                float rc = fmaxf(fmaxf(w0, w1), w2);
                cons += (rc > 0.5f && qr > 0.5f) ? rc * qr : 0.f;
            }
            w0 = w1; w1 = w2; w2 = pr;
        }
    }
    __syncthreads();

    // ---- tail violations: jg = c0+5, c0+6, c0+7 (need p8,p9,q8,q9,q10) ----
    {
        float p8, p9, q8, q9, q10;
        if (tid < BLK - 1) {
            int b = (tid + 1) * 3;
            p8 = on_h[b]; p9 = on_h[b + 1];
            q8 = off_h[b]; q9 = off_h[b + 1]; q10 = off_h[b + 2];
        } else {
            const float* onrow  = pon  + rowbase;
            const float* offrow = poff + rowbase;
            int h = C0 + COLS;
            p8  = (h     < T_LEN) ? fast_sig(onrow[h])      : 0.f;
            p9  = (h + 1 < T_LEN) ? fast_sig(onrow[h + 1])  : 0.f;
            q8  = (h     < T_LEN) ? fast_sig(offrow[h])     : 0.f;
            q9  = (h + 1 < T_LEN) ? fast_sig(offrow[h + 1]) : 0.f;
            q10 = (h + 2 < T_LEN) ? fast_sig(offrow[h + 2]) : 0.f;
        }
        // after the loop: w0=p5, w1=p6, w2=p7
        if (c0 + 5 <= T_LEN - 4) {
            float rc = fmaxf(fmaxf(w0, w1), w2);
            cons += (rc > 0.5f && q8 > 0.5f) ? rc * q8 : 0.f;
        }
        if (c0 + 6 <= T_LEN - 4) {
            float rc = fmaxf(fmaxf(w1, w2), p8);
            cons += (rc > 0.5f && q9 > 0.5f) ? rc * q9 : 0.f;
        }
        if (c0 + 7 <= T_LEN - 4) {
            float rc = fmaxf(fmaxf(w2, p8), p9);
            cons += (rc > 0.5f && q10 > 0.5f) ? rc * q10 : 0.f;
        }
    }

    // ---- block reduction: 9 partials ----
    float vals[9] = {on_pos, on_sp - on_tsp, on_cnt,
                     off_pos, off_sp - off_tsp, off_cnt,
                     on_psum, cons, on_psum - off_psum};
    #pragma unroll
    for (int v = 0; v < 9; v++) {
        float a = vals[v];
        for (int o = 32; o > 0; o >>= 1) a += __shfl_down(a, o, 64);
        vals[v] = a;
    }
    const int lane = tid & 63, wid = tid >> 6;
    if (lane == 0) {
        #pragma unroll
        for (int v = 0; v < 9; v++) part[wid][v] = vals[v];
    }
    __syncthreads();
    if (tid == 0) {
        float bsum[9];
        #pragma unroll
        for (int v = 0; v < 9; v++)
            bsum[v] = part[0][v] + part[1][v] + part[2][v] + part[3][v];
        float* gb = gbank + (blk & (NBANK - 1)) * 8;
        #pragma unroll
        for (int v = 0; v < 8; v++) atomicAdd(&gb[v], bsum[v]);   // device-scope, coherent
        atomicAdd(&rowdiff[row], bsum[8]);
        // order: data atomics must PERFORM before the counter bump
        asm volatile("s_waitcnt vmcnt(0)" ::: "memory");
        unsigned int old = atomicAdd(cnt, 1u);
        is_last = (old == GRID - 1u) ? 1 : 0;
    }
    __syncthreads();
    if (!is_last) return;

    // ================= last block: final reduction =================
    // All data atomics have performed (each block waited vmcnt(0) before cnt).
    // Read them back with agent-scope atomic loads (bypass incoherent caches).
    float rd = __hip_atomic_load(&rowdiff[tid], __ATOMIC_RELAXED,
                                 __HIP_MEMORY_SCOPE_AGENT);
    float pr_abs = fabsf(rd);                  // |sum_on - sum_off| for row tid
    {
        float a = pr_abs;
        for (int o = 32; o > 0; o >>= 1) a += __shfl_down(a, o, 64);
        if (lane == 0) part[wid][0] = a;
    }
    __syncthreads();
    if (tid == 0) {
        float pair_sum = part[0][0] + part[1][0] + part[2][0] + part[3][0];
        float t[8];
        #pragma unroll
        for (int v = 0; v < 8; v++) t[v] = 0.f;
        for (int b = 0; b < NBANK; b++) {
            #pragma unroll
            for (int v = 0; v < 8; v++)
                t[v] += __hip_atomic_load(&gbank[b * 8 + v], __ATOMIC_RELAXED,
                                          __HIP_MEMORY_SCOPE_AGENT);
        }
        const float N = (float)B_ROWS * (float)T_LEN;
        float pc = t[2], nc = N - pc;
        float pl = (pc > 0.f) ? t[0] / fmaxf(pc, 1.f) : 0.f;
        float nl = (nc > 0.f) ? t[1] / fmaxf(nc, 1.f) : 0.f;
        float onset_loss = 1.5f * pl + nl;
        float pc2 = t[5], nc2 = N - pc2;
        float pl2 = (pc2 > 0.f) ? t[3] / fmaxf(pc2, 1.f) : 0.f;
        float nl2 = (nc2 > 0.f) ? t[4] / fmaxf(nc2, 1.f) : 0.f;
        float offset_loss = 1.5f * pl2 + nl2;
        float cons_loss = t[7] / ((float)B_ROWS * (float)(T_LEN - 3));
        float pair_loss = pair_sum / (float)B_ROWS;
        float mean_on   = t[6] / N;
        float sparsity  = 0.f;   // SPARSE_W == 0
        float total = 5.0f * onset_loss + 3.0f * offset_loss + 0.1f * cons_loss
                    + 0.05f * pair_loss + sparsity;
        out[0] = onset_loss;
        out[1] = offset_loss;
        out[2] = cons_loss;
        out[3] = pair_loss;
        out[4] = sparsity;
        out[5] = mean_on;
        out[6] = total;
    }
}

extern "C" void kernel_launch(void* const* d_in, const int* in_sizes, int n_in,
                              void* d_out, int out_size, void* d_ws, size_t ws_size,
                              hipStream_t stream) {
    const float* pon  = (const float*)d_in[0];
    const float* poff = (const float*)d_in[1];
    const float* ton  = (const float*)d_in[2];
    const float* toff = (const float*)d_in[3];
    float* ws = (float*)d_ws;
    // zero gbank (NBANK*8) + rowdiff (B_ROWS) + cnt : (64+256)*4+4 = 1284 B
    hipMemsetAsync(ws, 0, (NBANK * 8 + B_ROWS) * sizeof(float) + sizeof(unsigned int),
                   stream);
    loss_fused<<<GRID, BLK, 0, stream>>>(pon, poff, ton, toff, ws, (float*)d_out);
}

// Round 6
// 23.864 us; speedup vs baseline: 5.1739x; 5.1739x over previous
//
#include <hip/hip_runtime.h>
#include <math.h>

#define T_LEN 16384
#define B_ROWS 256
#define BLK 256
#define EPT 8                       // elements per thread
#define COLS (BLK * EPT)            // 2048 columns per block
#define SEG (T_LEN / COLS)          // 8 segments per row
#define GRID (B_ROWS * SEG)         // 2048 blocks
#define WSTRIDE 12                  // floats per block-partial record (48B, float4-able)

#define LOG2E 1.44269504088896340f
#define LN2   0.69314718055994531f

// fast sigmoid: 1 v_exp + 1 v_rcp
__device__ __forceinline__ float fast_sig(float x) {
    float e = __builtin_amdgcn_exp2f(fabsf(x) * -LOG2E);
    float r = __builtin_amdgcn_rcpf(1.0f + e);
    return (x >= 0.f) ? r : e * r;
}

// NOTE R3-R5 lesson: single-kernel fan-in via device-scope atomics/fences costs
// ~100us of drain (2048 same-line RMWs serialized). Two dispatches is 5x faster.

__global__ __launch_bounds__(BLK) void loss_partial(
    const float* __restrict__ pon, const float* __restrict__ poff,
    const float* __restrict__ ton, const float* __restrict__ toff,
    float* __restrict__ ws)
{
    const int blk = blockIdx.x;
    const int row = blk >> 3;            // SEG = 8
    const int s   = blk & 7;
    const int tid = threadIdx.x;
    const int C0  = s * COLS;            // segment start (row-local col)
    const int c0  = C0 + tid * EPT;      // this thread's first col
    const size_t rowbase = (size_t)row * T_LEN;

    __shared__ float on_h[BLK * 3];      // each thread's first 3 onset probs
    __shared__ float off_h[BLK * 3];     // each thread's first 3 offset probs
    __shared__ float part[4][9];

    // accumulators (arithmetic form, t/u are exactly 0.0 or 1.0)
    float on_sp = 0.f, on_tsp = 0.f, on_pos = 0.f, on_cnt = 0.f, on_psum = 0.f;
    float off_sp = 0.f, off_tsp = 0.f, off_pos = 0.f, off_cnt = 0.f, off_psum = 0.f;
    float cons = 0.f;
    float w0 = 0.f, w1 = 0.f, w2 = 0.f;  // rolling window of last 3 onset probs

    const float4* pon4  = (const float4*)(pon  + rowbase + c0);
    const float4* poff4 = (const float4*)(poff + rowbase + c0);
    const float4* ton4  = (const float4*)(ton  + rowbase + c0);
    const float4* toff4 = (const float4*)(toff + rowbase + c0);

    #pragma unroll
    for (int k = 0; k < EPT / 4; k++) {
        float4 xo = pon4[k], xf = poff4[k], to = ton4[k], tf = toff4[k];
        float xs[4] = {xo.x, xo.y, xo.z, xo.w};
        float fs[4] = {xf.x, xf.y, xf.z, xf.w};
        float ts[4] = {to.x, to.y, to.z, to.w};
        float us[4] = {tf.x, tf.y, tf.z, tf.w};
        #pragma unroll
        for (int j = 0; j < 4; j++) {
            const int i = 4 * k + j;      // compile-time
            // ---- onset: softplus + sigmoid via exp2/rcp/log2 HW ops ----
            float x  = xs[j], t = ts[j];
            float e  = __builtin_amdgcn_exp2f(fabsf(x) * -LOG2E);
            float r  = __builtin_amdgcn_rcpf(1.0f + e);
            float sp = fmaf(-LN2, __builtin_amdgcn_logf(r), fmaxf(x, 0.f)); // softplus(x)
            on_sp  += sp;
            on_tsp += t * sp;
            on_pos += t * fminf(sp - x, 5.0f);
            on_cnt += t;
            float pr = (x >= 0.f) ? r : e * r;
            on_psum += pr;
            // ---- offset ----
            float y  = fs[j], u = us[j];
            float e2 = __builtin_amdgcn_exp2f(fabsf(y) * -LOG2E);
            float r2 = __builtin_amdgcn_rcpf(1.0f + e2);
            float sp2 = fmaf(-LN2, __builtin_amdgcn_logf(r2), fmaxf(y, 0.f));
            off_sp  += sp2;
            off_tsp += u * sp2;
            off_pos += u * fminf(sp2 - y, 5.0f);
            off_cnt += u;
            float qr = (y >= 0.f) ? r2 : e2 * r2;
            off_psum += qr;
            // ---- halo stash (compile-time branch) ----
            if (i < 3) { on_h[tid * 3 + i] = pr; off_h[tid * 3 + i] = qr; }
            // ---- in-chunk violations: jg = c0+i-3, i>=3 ----
            if (i >= 3) {
                float rc = fmaxf(fmaxf(w0, w1), w2);
                cons += (rc > 0.5f && qr > 0.5f) ? rc * qr : 0.f;
            }
            w0 = w1; w1 = w2; w2 = pr;
        }
    }
    __syncthreads();

    // ---- tail violations: jg = c0+5, c0+6, c0+7 (need p8,p9,q8,q9,q10) ----
    {
        float p8, p9, q8, q9, q10;
        if (tid < BLK - 1) {
            int b = (tid + 1) * 3;
            p8 = on_h[b]; p9 = on_h[b + 1];
            q8 = off_h[b]; q9 = off_h[b + 1]; q10 = off_h[b + 2];
        } else {
            const float* onrow  = pon  + rowbase;
            const float* offrow = poff + rowbase;
            int h = C0 + COLS;
            p8  = (h     < T_LEN) ? fast_sig(onrow[h])      : 0.f;
            p9  = (h + 1 < T_LEN) ? fast_sig(onrow[h + 1])  : 0.f;
            q8  = (h     < T_LEN) ? fast_sig(offrow[h])     : 0.f;
            q9  = (h + 1 < T_LEN) ? fast_sig(offrow[h + 1]) : 0.f;
            q10 = (h + 2 < T_LEN) ? fast_sig(offrow[h + 2]) : 0.f;
        }
        // after the loop: w0=p5, w1=p6, w2=p7
        if (c0 + 5 <= T_LEN - 4) {
            float rc = fmaxf(fmaxf(w0, w1), w2);
            cons += (rc > 0.5f && q8 > 0.5f) ? rc * q8 : 0.f;
        }
        if (c0 + 6 <= T_LEN - 4) {
            float rc = fmaxf(fmaxf(w1, w2), p8);
            cons += (rc > 0.5f && q9 > 0.5f) ? rc * q9 : 0.f;
        }
        if (c0 + 7 <= T_LEN - 4) {
            float rc = fmaxf(fmaxf(w2, p8), p9);
            cons += (rc > 0.5f && q10 > 0.5f) ? rc * q10 : 0.f;
        }
    }

    // ---- block reduction: 9 partials ----
    float vals[9] = {on_pos, on_sp - on_tsp, on_cnt,
                     off_pos, off_sp - off_tsp, off_cnt,
                     on_psum, off_psum, cons};
    #pragma unroll
    for (int v = 0; v < 9; v++) {
        float a = vals[v];
        for (int o = 32; o > 0; o >>= 1) a += __shfl_down(a, o, 64);
        vals[v] = a;
    }
    const int lane = tid & 63, wid = tid >> 6;
    if (lane == 0) {
        #pragma unroll
        for (int v = 0; v < 9; v++) part[wid][v] = vals[v];
    }
    __syncthreads();
    if (tid < 12) {
        // 12 threads write the padded 12-float record (3 pad lanes write 0)
        float val = 0.f;
        if (tid < 9) val = part[0][tid] + part[1][tid] + part[2][tid] + part[3][tid];
        ws[(size_t)blk * WSTRIDE + tid] = val;
    }
}

__global__ __launch_bounds__(256) void finalize_k(const float* __restrict__ ws,
                                                  float* __restrict__ out)
{
    const int r = threadIdx.x;   // one row per thread
    float a[9];
    #pragma unroll
    for (int v = 0; v < 9; v++) a[v] = 0.f;
    // row r owns blocks r*8 .. r*8+7, each a 12-float (3x float4) record
    const float4* p4 = (const float4*)(ws + (size_t)r * SEG * WSTRIDE);
    #pragma unroll
    for (int s = 0; s < SEG; s++) {
        float4 f0 = p4[s * 3 + 0];
        float4 f1 = p4[s * 3 + 1];
        float4 f2 = p4[s * 3 + 2];
        a[0] += f0.x; a[1] += f0.y; a[2] += f0.z; a[3] += f0.w;
        a[4] += f1.x; a[5] += f1.y; a[6] += f1.z; a[7] += f1.w;
        a[8] += f2.x;
    }
    float red[9];
    red[0] = a[0]; red[1] = a[1]; red[2] = a[2];
    red[3] = a[3]; red[4] = a[4]; red[5] = a[5];
    red[6] = a[6];
    red[7] = a[8];
    red[8] = fabsf(a[6] - a[7]);          // per-row |sum_on - sum_off|
    #pragma unroll
    for (int v = 0; v < 9; v++) {
        float x = red[v];
        for (int o = 32; o > 0; o >>= 1) x += __shfl_down(x, o, 64);
        red[v] = x;
    }
    __shared__ float part[4][9];
    const int lane = r & 63, wid = r >> 6;
    if (lane == 0) {
        #pragma unroll
        for (int v = 0; v < 9; v++) part[wid][v] = red[v];
    }
    __syncthreads();
    if (r == 0) {
        float t[9];
        #pragma unroll
        for (int v = 0; v < 9; v++)
            t[v] = part[0][v] + part[1][v] + part[2][v] + part[3][v];
        const float N = (float)B_ROWS * (float)T_LEN;
        float pc = t[2], nc = N - pc;
        float pl = (pc > 0.f) ? t[0] / fmaxf(pc, 1.f) : 0.f;
        float nl = (nc > 0.f) ? t[1] / fmaxf(nc, 1.f) : 0.f;
        float onset_loss = 1.5f * pl + nl;
        float pc2 = t[5], nc2 = N - pc2;
        float pl2 = (pc2 > 0.f) ? t[3] / fmaxf(pc2, 1.f) : 0.f;
        float nl2 = (nc2 > 0.f) ? t[4] / fmaxf(nc2, 1.f) : 0.f;
        float offset_loss = 1.5f * pl2 + nl2;
        float cons_loss = t[7] / ((float)B_ROWS * (float)(T_LEN - 3));
        float pair_loss = t[8] / (float)B_ROWS;
        float mean_on   = t[6] / N;
        float sparsity  = 0.f;   // SPARSE_W == 0
        float total = 5.0f * onset_loss + 3.0f * offset_loss + 0.1f * cons_loss
                    + 0.05f * pair_loss + sparsity;
        out[0] = onset_loss;
        out[1] = offset_loss;
        out[2] = cons_loss;
        out[3] = pair_loss;
        out[4] = sparsity;
        out[5] = mean_on;
        out[6] = total;
    }
}

extern "C" void kernel_launch(void* const* d_in, const int* in_sizes, int n_in,
                              void* d_out, int out_size, void* d_ws, size_t ws_size,
                              hipStream_t stream) {
    const float* pon  = (const float*)d_in[0];
    const float* poff = (const float*)d_in[1];
    const float* ton  = (const float*)d_in[2];
    const float* toff = (const float*)d_in[3];
    float* ws = (float*)d_ws;   // GRID * 12 floats = 98.3 KB
    loss_partial<<<GRID, BLK, 0, stream>>>(pon, poff, ton, toff, ws);
    finalize_k<<<1, BLK, 0, stream>>>(ws, (float*)d_out);
}

// Round 7
// 21.819 us; speedup vs baseline: 5.6588x; 1.0937x over previous
//
#include <hip/hip_runtime.h>
#include <math.h>

#define T_LEN 16384
#define B_ROWS 256
#define BLK 256
#define EPT 16                      // elements per thread
#define COLS (BLK * EPT)            // 4096 columns per block
#define SEG (T_LEN / COLS)          // 4 segments per row
#define GRID (B_ROWS * SEG)         // 1024 blocks
#define WSTRIDE 12                  // floats per block-partial record (48B)

#define LOG2E 1.44269504088896340f
#define LN2   0.69314718055994531f

typedef float v4f __attribute__((ext_vector_type(4)));

__device__ __forceinline__ float fast_sig(float x) {
    float e = __builtin_amdgcn_exp2f(fabsf(x) * -LOG2E);
    float r = __builtin_amdgcn_rcpf(1.0f + e);
    return (x >= 0.f) ? r : e * r;
}

// R3-R5 lesson: single-kernel atomic fan-in costs ~100us drain -> two dispatches.
// R7: EPT=16 + depth-2 software pipeline (4 batches) so VALU overlaps memory;
// EPT=8 had only 2 batches -> grid-wide convoy (VALU+mem serialized ~ 18us).

// process 4 elements (absolute in-thread indices IB..IB+3)
#define BATCH(IB, XO, XF, TO, TF)                                            \
    _Pragma("unroll")                                                        \
    for (int j = 0; j < 4; j++) {                                            \
        const int i = (IB) + j;                                              \
        float x  = (XO)[j], t = (TO)[j];                                     \
        float e  = __builtin_amdgcn_exp2f(fabsf(x) * -LOG2E);                \
        float r  = __builtin_amdgcn_rcpf(1.0f + e);                          \
        float sp = fmaf(-LN2, __builtin_amdgcn_logf(r), fmaxf(x, 0.f));      \
        on_sp  += sp;                                                        \
        on_tsp += t * sp;                                                    \
        on_pos += t * fminf(sp - x, 5.0f);                                   \
        on_cnt += t;                                                         \
        float pr = (x >= 0.f) ? r : e * r;                                   \
        on_psum += pr;                                                       \
        float y  = (XF)[j], u = (TF)[j];                                     \
        float e2 = __builtin_amdgcn_exp2f(fabsf(y) * -LOG2E);                \
        float r2 = __builtin_amdgcn_rcpf(1.0f + e2);                         \
        float sp2 = fmaf(-LN2, __builtin_amdgcn_logf(r2), fmaxf(y, 0.f));    \
        off_sp  += sp2;                                                      \
        off_tsp += u * sp2;                                                  \
        off_pos += u * fminf(sp2 - y, 5.0f);                                 \
        off_cnt += u;                                                        \
        float qr = (y >= 0.f) ? r2 : e2 * r2;                                \
        off_psum += qr;                                                      \
        if (i < 3) { on_h[tid * 3 + i] = pr; off_h[tid * 3 + i] = qr; }      \
        if (i >= 3) {                                                        \
            float rc = fmaxf(fmaxf(w0, w1), w2);                             \
            cons += (rc > 0.5f && qr > 0.5f) ? rc * qr : 0.f;                \
        }                                                                    \
        w0 = w1; w1 = w2; w2 = pr;                                           \
    }

__global__ __launch_bounds__(BLK) void loss_partial(
    const float* __restrict__ pon, const float* __restrict__ poff,
    const float* __restrict__ ton, const float* __restrict__ toff,
    float* __restrict__ ws)
{
    const int blk = blockIdx.x;
    const int row = blk >> 2;            // SEG = 4
    const int s   = blk & 3;
    const int tid = threadIdx.x;
    const int C0  = s * COLS;            // segment start (row-local col)
    const int c0  = C0 + tid * EPT;      // this thread's first col
    const size_t rowbase = (size_t)row * T_LEN;

    __shared__ float on_h[BLK * 3];      // each thread's first 3 onset probs
    __shared__ float off_h[BLK * 3];     // each thread's first 3 offset probs
    __shared__ float part[4][9];

    float on_sp = 0.f, on_tsp = 0.f, on_pos = 0.f, on_cnt = 0.f, on_psum = 0.f;
    float off_sp = 0.f, off_tsp = 0.f, off_pos = 0.f, off_cnt = 0.f, off_psum = 0.f;
    float cons = 0.f;
    float w0 = 0.f, w1 = 0.f, w2 = 0.f;  // rolling window of last 3 onset probs

    const float* pb = pon  + rowbase + c0;
    const float* fb = poff + rowbase + c0;
    const float* tb = ton  + rowbase + c0;
    const float* ub = toff + rowbase + c0;

    // ---- depth-2 pipelined stream: 4 batches, 2 named register sets ----
    v4f a0 = *(const v4f*)(pb + 0),  a1 = *(const v4f*)(fb + 0);
    v4f a2 = *(const v4f*)(tb + 0),  a3 = *(const v4f*)(ub + 0);
    v4f b0 = *(const v4f*)(pb + 4),  b1 = *(const v4f*)(fb + 4);
    v4f b2 = *(const v4f*)(tb + 4),  b3 = *(const v4f*)(ub + 4);

    BATCH(0, a0, a1, a2, a3)                       // compute batch 0
    a0 = *(const v4f*)(pb + 8);  a1 = *(const v4f*)(fb + 8);   // load batch 2
    a2 = *(const v4f*)(tb + 8);  a3 = *(const v4f*)(ub + 8);
    BATCH(4, b0, b1, b2, b3)                       // compute batch 1
    b0 = *(const v4f*)(pb + 12); b1 = *(const v4f*)(fb + 12);  // load batch 3
    b2 = *(const v4f*)(tb + 12); b3 = *(const v4f*)(ub + 12);
    BATCH(8, a0, a1, a2, a3)                       // compute batch 2
    BATCH(12, b0, b1, b2, b3)                      // compute batch 3

    __syncthreads();

    // ---- tail violations: jg = c0+13, c0+14, c0+15 (need p16,p17,q16,q17,q18) ----
    {
        float p16, p17, q16, q17, q18;
        if (tid < BLK - 1) {
            int b = (tid + 1) * 3;
            p16 = on_h[b];  p17 = on_h[b + 1];
            q16 = off_h[b]; q17 = off_h[b + 1]; q18 = off_h[b + 2];
        } else {
            const float* onrow  = pon  + rowbase;
            const float* offrow = poff + rowbase;
            int h = C0 + COLS;
            p16 = (h     < T_LEN) ? fast_sig(onrow[h])      : 0.f;
            p17 = (h + 1 < T_LEN) ? fast_sig(onrow[h + 1])  : 0.f;
            q16 = (h     < T_LEN) ? fast_sig(offrow[h])     : 0.f;
            q17 = (h + 1 < T_LEN) ? fast_sig(offrow[h + 1]) : 0.f;
            q18 = (h + 2 < T_LEN) ? fast_sig(offrow[h + 2]) : 0.f;
        }
        // after the loop: w0=p13, w1=p14, w2=p15
        if (c0 + 13 <= T_LEN - 4) {
            float rc = fmaxf(fmaxf(w0, w1), w2);
            cons += (rc > 0.5f && q16 > 0.5f) ? rc * q16 : 0.f;
        }
        if (c0 + 14 <= T_LEN - 4) {
            float rc = fmaxf(fmaxf(w1, w2), p16);
            cons += (rc > 0.5f && q17 > 0.5f) ? rc * q17 : 0.f;
        }
        if (c0 + 15 <= T_LEN - 4) {
            float rc = fmaxf(fmaxf(w2, p16), p17);
            cons += (rc > 0.5f && q18 > 0.5f) ? rc * q18 : 0.f;
        }
    }

    // ---- block reduction: 9 partials ----
    float vals[9] = {on_pos, on_sp - on_tsp, on_cnt,
                     off_pos, off_sp - off_tsp, off_cnt,
                     on_psum, off_psum, cons};
    #pragma unroll
    for (int v = 0; v < 9; v++) {
        float a = vals[v];
        for (int o = 32; o > 0; o >>= 1) a += __shfl_down(a, o, 64);
        vals[v] = a;
    }
    const int lane = tid & 63, wid = tid >> 6;
    if (lane == 0) {
        #pragma unroll
        for (int v = 0; v < 9; v++) part[wid][v] = vals[v];
    }
    __syncthreads();
    if (tid < 12) {
        float val = 0.f;
        if (tid < 9) val = part[0][tid] + part[1][tid] + part[2][tid] + part[3][tid];
        ws[(size_t)blk * WSTRIDE + tid] = val;
    }
}

__global__ __launch_bounds__(256) void finalize_k(const float* __restrict__ ws,
                                                  float* __restrict__ out)
{
    const int r = threadIdx.x;   // one row per thread
    float a[9];
    #pragma unroll
    for (int v = 0; v < 9; v++) a[v] = 0.f;
    // row r owns blocks r*SEG .. r*SEG+SEG-1, each a 12-float (3x float4) record
    const float4* p4 = (const float4*)(ws + (size_t)r * SEG * WSTRIDE);
    #pragma unroll
    for (int s = 0; s < SEG; s++) {
        float4 f0 = p4[s * 3 + 0];
        float4 f1 = p4[s * 3 + 1];
        float4 f2 = p4[s * 3 + 2];
        a[0] += f0.x; a[1] += f0.y; a[2] += f0.z; a[3] += f0.w;
        a[4] += f1.x; a[5] += f1.y; a[6] += f1.z; a[7] += f1.w;
        a[8] += f2.x;
    }
    float red[9];
    red[0] = a[0]; red[1] = a[1]; red[2] = a[2];
    red[3] = a[3]; red[4] = a[4]; red[5] = a[5];
    red[6] = a[6];
    red[7] = a[8];
    red[8] = fabsf(a[6] - a[7]);          // per-row |sum_on - sum_off|
    #pragma unroll
    for (int v = 0; v < 9; v++) {
        float x = red[v];
        for (int o = 32; o > 0; o >>= 1) x += __shfl_down(x, o, 64);
        red[v] = x;
    }
    __shared__ float part[4][9];
    const int lane = r & 63, wid = r >> 6;
    if (lane == 0) {
        #pragma unroll
        for (int v = 0; v < 9; v++) part[wid][v] = red[v];
    }
    __syncthreads();
    if (r == 0) {
        float t[9];
        #pragma unroll
        for (int v = 0; v < 9; v++)
            t[v] = part[0][v] + part[1][v] + part[2][v] + part[3][v];
        const float N = (float)B_ROWS * (float)T_LEN;
        float pc = t[2], nc = N - pc;
        float pl = (pc > 0.f) ? t[0] / fmaxf(pc, 1.f) : 0.f;
        float nl = (nc > 0.f) ? t[1] / fmaxf(nc, 1.f) : 0.f;
        float onset_loss = 1.5f * pl + nl;
        float pc2 = t[5], nc2 = N - pc2;
        float pl2 = (pc2 > 0.f) ? t[3] / fmaxf(pc2, 1.f) : 0.f;
        float nl2 = (nc2 > 0.f) ? t[4] / fmaxf(nc2, 1.f) : 0.f;
        float offset_loss = 1.5f * pl2 + nl2;
        float cons_loss = t[7] / ((float)B_ROWS * (float)(T_LEN - 3));
        float pair_loss = t[8] / (float)B_ROWS;
        float mean_on   = t[6] / N;
        float sparsity  = 0.f;   // SPARSE_W == 0
        float total = 5.0f * onset_loss + 3.0f * offset_loss + 0.1f * cons_loss
                    + 0.05f * pair_loss + sparsity;
        out[0] = onset_loss;
        out[1] = offset_loss;
        out[2] = cons_loss;
        out[3] = pair_loss;
        out[4] = sparsity;
        out[5] = mean_on;
        out[6] = total;
    }
}

extern "C" void kernel_launch(void* const* d_in, const int* in_sizes, int n_in,
                              void* d_out, int out_size, void* d_ws, size_t ws_size,
                              hipStream_t stream) {
    const float* pon  = (const float*)d_in[0];
    const float* poff = (const float*)d_in[1];
    const float* ton  = (const float*)d_in[2];
    const float* toff = (const float*)d_in[3];
    float* ws = (float*)d_ws;   // GRID * 12 floats = 49.2 KB
    loss_partial<<<GRID, BLK, 0, stream>>>(pon, poff, ton, toff, ws);
    finalize_k<<<1, BLK, 0, stream>>>(ws, (float*)d_out);
}